// Round 9
// baseline (179.882 us; speedup 1.0000x reference)
//
#include <hip/hip_runtime.h>
#include <hip/hip_bf16.h>
#include <math.h>

typedef float f32x4 __attribute__((ext_vector_type(4)));
typedef int   i32x4 __attribute__((ext_vector_type(4)));
typedef int   i32x8 __attribute__((ext_vector_type(8)));
typedef float f32x2 __attribute__((ext_vector_type(2)));

#define MTOT 16384
#define HALF 8192
#define KDIM 256                  /* bytes per row in fp8 Z */
#define BT 256                    /* tile edge */
#define NB (MTOT / BT)            /* 64 tile-rows */
#define NBLK (NB * (NB + 1) / 2)  /* 2080 upper-triangle tiles */
#define GRID 256                  /* persistent blocks, 1 per CU (128KB LDS) */
#define NPART (GRID * 8)          /* one partial per wave */

#define GLDS16(g, l) __builtin_amdgcn_global_load_lds(                      \
    (const __attribute__((address_space(1))) void*)(g),                     \
    (__attribute__((address_space(3))) void*)(l), 16, 0, 0)

// s_waitcnt immediates (gfx9: vm[3:0] bits3:0, vm[5:4] bits15:14; exp 6:4;
// lgkm 11:8). Unconstrained fields set to max.
#define WAIT_VM10()  __builtin_amdgcn_s_waitcnt(0x0F7A)  /* vmcnt(10) */
#define WAIT_VM8()   __builtin_amdgcn_s_waitcnt(0x0F78)  /* vmcnt(8)  */
#define WAIT_VM0()   __builtin_amdgcn_s_waitcnt(0x0F70)  /* vmcnt(0)  */
#define WAIT_LGKM0() __builtin_amdgcn_s_waitcnt(0xC07F)  /* lgkmcnt(0) */
#define BARRIER()    __builtin_amdgcn_s_barrier()

// ---------------------------------------------------------------------------
// Pass 1: fp32 -> fp8 e4m3 (OCP, HW cvt); row norms FROM the quantized
// values so the kernel-matrix diagonal cancels to d2 ~ 0 despite fp8 MFMA.
// ---------------------------------------------------------------------------
__global__ __launch_bounds__(256) void convert_kernel(
    const float* __restrict__ Nmat, const float* __restrict__ Rmat,
    unsigned int* __restrict__ Z, float* __restrict__ x2) {
  const int lane = threadIdx.x & 63;
  const int wv = threadIdx.x >> 6;
  const int row = blockIdx.x * 4 + wv;          // 0..16383
  const float* src = (row < HALF) ? (Nmat + (size_t)row * KDIM)
                                  : (Rmat + (size_t)(row - HALF) * KDIM);
  float4 v = *(const float4*)(src + lane * 4);
  int pk = __builtin_amdgcn_cvt_pk_fp8_f32(v.x, v.y, 0, false);
  pk = __builtin_amdgcn_cvt_pk_fp8_f32(v.z, v.w, pk, true);
  Z[(size_t)row * (KDIM / 4) + lane] = (unsigned int)pk;
  f32x2 d01 = __builtin_amdgcn_cvt_pk_f32_fp8(pk, false);
  f32x2 d23 = __builtin_amdgcn_cvt_pk_f32_fp8(pk, true);
  float sq = d01[0] * d01[0] + d01[1] * d01[1] + d23[0] * d23[0] + d23[1] * d23[1];
  #pragma unroll
  for (int off = 32; off; off >>= 1) sq += __shfl_down(sq, off);
  if (lane == 0) x2[row] = sq;
}

// One K=128 MFMA step over a staged half — TEXTUAL MACRO, not a function:
// rounds 6-8 passed acc by reference into a lambda, which took the array's
// address, defeated SROA, and left acc in scratch memory (~80 MB/launch of
// HBM scratch traffic = the whole regression; no occupancy attribute could
// fix it because it was never register spilling). Straight-line unrolled
// code with constant indices keeps all 32 f32x4 accumulators in registers.
#define COMPUTE_HALF(as, bs)                                                  \
  {                                                                           \
    i32x8 bf[4];                                                              \
    _Pragma("unroll")                                                         \
    for (int tn = 0; tn < 4; ++tn) {                                          \
      int row = wn * 64 + tn * 16 + fr;                                       \
      const unsigned char* rb = (bs) + row * 128;                             \
      i32x4 lo = *(const i32x4*)(rb + (((2 * fq) ^ key) * 16));               \
      i32x4 hi = *(const i32x4*)(rb + (((2 * fq + 1) ^ key) * 16));           \
      bf[tn] = __builtin_shufflevector(lo, hi, 0, 1, 2, 3, 4, 5, 6, 7);       \
    }                                                                         \
    _Pragma("unroll")                                                         \
    for (int tm = 0; tm < 8; ++tm) {                                          \
      int row = wm * 128 + tm * 16 + fr;                                      \
      const unsigned char* rb = (as) + row * 128;                             \
      i32x4 lo = *(const i32x4*)(rb + (((2 * fq) ^ key) * 16));               \
      i32x4 hi = *(const i32x4*)(rb + (((2 * fq + 1) ^ key) * 16));           \
      i32x8 af = __builtin_shufflevector(lo, hi, 0, 1, 2, 3, 4, 5, 6, 7);     \
      _Pragma("unroll")                                                       \
      for (int tn = 0; tn < 4; ++tn)                                          \
        acc[tm][tn] = __builtin_amdgcn_mfma_scale_f32_16x16x128_f8f6f4(       \
            af, bf[tn], acc[tm][tn], 0, 0,                                    \
            0, 0x7F7F7F7F, 0, 0x7F7F7F7F);                                    \
    }                                                                         \
  }

// ---------------------------------------------------------------------------
// Pass 2: persistent 256x256-tile Z Z^T (MX-fp8 16x16x128, unit scales),
// 2-deep K-half pipeline, raw s_barrier + manual vmcnt (logic proven R6-R8).
// Per-wave GLDS groups: h0=8, h1=8, x2=2 => loop-top wait vmcnt(10)
// (younger = h1+x2), mid wait vmcnt(8) (younger = next h0), last vmcnt(0).
// waves_per_eu(2,2) matches residency (8 waves/block, 1 block/CU by LDS)
// and opens the 256-reg unified VGPR+AGPR budget per wave.
// ---------------------------------------------------------------------------
__global__ __launch_bounds__(512)
__attribute__((amdgpu_waves_per_eu(2, 2)))
void mmd_gemm(
    const unsigned char* __restrict__ Z, const float* __restrict__ x2,
    float* __restrict__ partials) {
  __shared__ unsigned char As0[BT * 128], Bs0[BT * 128];  // K-half 0, 64 KB
  __shared__ unsigned char As1[BT * 128], Bs1[BT * 128];  // K-half 1, 64 KB
  __shared__ float Xr[BT], Xc[BT];                        // x2 of tile rows/cols

  const int tid  = threadIdx.x;
  const int lane = tid & 63;
  const int wid  = tid >> 6;       // 0..7
  const int wm   = wid >> 2;       // wave row (0..1): rows wm*128..+128
  const int wn   = wid & 3;        // wave col (0..3): cols wn*64..+64
  const int fr   = lane & 15;
  const int fq   = lane >> 4;      // 0..3
  const int lr   = lane >> 3;      // staging local row 0..7
  const int ls   = lane & 7;       // staging slot 0..7
  const int key  = fr & 7;         // read-side bank-swizzle key

  // Stage one K-half: 8 GLDS16 per wave (4 A + 4 B). Instr i covers rows
  // 8i..8i+7; slot ls of row gr holds chunk ls^(gr&7) (gr&7 == lr).
  // (Lambda captures only scalars/pointers - no array address escapes.)
  auto issue_half = [&](const unsigned char* Ab, const unsigned char* Bb,
                        int kk, unsigned char* as, unsigned char* bs) {
    #pragma unroll
    for (int q = 0; q < 4; ++q) {
      int i = wid * 4 + q;
      int gr = i * 8 + lr;
      int c = ls ^ lr;
      GLDS16(Ab + (size_t)gr * KDIM + kk + c * 16, as + i * 1024);
    }
    #pragma unroll
    for (int q = 0; q < 4; ++q) {
      int i = wid * 4 + q;
      int gr = i * 8 + lr;
      int c = ls ^ lr;
      GLDS16(Bb + (size_t)gr * KDIM + kk + c * 16, bs + i * 1024);
    }
  };

  // Stage x2 row/col slices: 2 GLDS16 per wave (all waves write identical
  // data to the same LDS - benign, keeps per-wave vmcnt counts uniform).
  auto issue_x2 = [&](int bm_, int bn_) {
    GLDS16(x2 + bm_ * BT + lane * 4, Xr);
    GLDS16(x2 + bn_ * BT + lane * 4, Xc);
  };

  auto decode = [](int t, int& bm_, int& bn_) {
    int u = NBLK - 1 - t;
    int rr = (int)((sqrtf(8.0f * (float)u + 1.0f) - 1.0f) * 0.5f);
    while (rr * (rr + 1) / 2 > u) --rr;
    while ((rr + 1) * (rr + 2) / 2 <= u) ++rr;
    bm_ = NB - 1 - rr;
    bn_ = bm_ + (t - (bm_ * NB - bm_ * (bm_ - 1) / 2));
  };

  float total = 0.f;

  int idx = blockIdx.x;
  int bm, bn;
  decode(idx, bm, bn);
  const unsigned char* Ab = Z + (size_t)bm * BT * KDIM;
  const unsigned char* Bb = Z + (size_t)bn * BT * KDIM;
  issue_half(Ab, Bb, 0,   As0, Bs0);   // 8/wave
  issue_half(Ab, Bb, 128, As1, Bs1);   // 8/wave
  issue_x2(bm, bn);                    // 2/wave

  while (true) {
    const int nidx = idx + GRID;
    const bool haveNext = (nidx < NBLK);
    int nm = 0, nn = 0;
    const unsigned char *nAb = nullptr, *nBb = nullptr;
    if (haveNext) {
      decode(nidx, nm, nn);
      nAb = Z + (size_t)nm * BT * KDIM;
      nBb = Z + (size_t)nn * BT * KDIM;
    }

    f32x4 acc[8][4];
    #pragma unroll
    for (int i = 0; i < 8; ++i)
      #pragma unroll
      for (int j = 0; j < 4; ++j)
        acc[i][j] = (f32x4){0.f, 0.f, 0.f, 0.f};

    WAIT_VM10();                // h0 done (younger: h1=8 + x2=2)
    BARRIER();
    COMPUTE_HALF(As0, Bs0);
    WAIT_LGKM0();               // my buf0 reads retired
    BARRIER();                  // everyone's buf0 reads retired
    if (haveNext) issue_half(nAb, nBb, 0, As0, Bs0);   // prefetch next h0

    WAIT_VM8();                 // h1 + x2 done (younger: next h0 = 8)...
    if (!haveNext) WAIT_VM0();  // ...or full drain on the last tile
    BARRIER();
    COMPUTE_HALF(As1, Bs1);

    // Epilogue (LDS-only): m = 2s - x2r - x2c = -d2; exp iff any m > -80.
    float amax = -1e30f;
    #pragma unroll
    for (int tm = 0; tm < 8; ++tm) {
      float4 xr = *(const float4*)(Xr + wm * 128 + tm * 16 + fq * 4);
      #pragma unroll
      for (int tn = 0; tn < 4; ++tn) {
        float xc = Xc[wn * 64 + tn * 16 + fr];
        #pragma unroll
        for (int v = 0; v < 4; ++v) {
          float m = 2.f * acc[tm][tn][v] - ((const float*)&xr)[v] - xc;
          amax = fmaxf(amax, m);
        }
      }
    }
    if (__any(amax > -80.f)) {
      float wgt = ((bm < NB / 2) == (bn < NB / 2)) ? 1.f : -1.f;
      if (bm != bn) wgt *= 2.f;
      float p = 0.f;
      #pragma unroll
      for (int tm = 0; tm < 8; ++tm) {
        float4 xr = *(const float4*)(Xr + wm * 128 + tm * 16 + fq * 4);
        #pragma unroll
        for (int tn = 0; tn < 4; ++tn) {
          float xc = Xc[wn * 64 + tn * 16 + fr];
          #pragma unroll
          for (int v = 0; v < 4; ++v) {
            float m = 2.f * acc[tm][tn][v] - ((const float*)&xr)[v] - xc;
            p += exp2f(fminf(m, 0.f) * 1.442695041f);
          }
        }
      }
      total += p * wgt;
    }

    WAIT_LGKM0();               // my buf1/Xr/Xc reads retired
    BARRIER();                  // everyone's retired
    if (!haveNext) break;
    issue_half(nAb, nBb, 128, As1, Bs1);   // prefetch next h1 (8/wave)
    issue_x2(nm, nn);                      // prefetch next x2 (2/wave)
    idx = nidx; bm = nm; bn = nn; Ab = nAb; Bb = nBb;
  }

  #pragma unroll
  for (int off = 32; off; off >>= 1) total += __shfl_down(total, off);
  if (lane == 0) partials[blockIdx.x * 8 + wid] = total;
}

// ---------------------------------------------------------------------------
// Pass 3: reduce the 2048 per-wave partials, sqrt, store the scalar.
// ---------------------------------------------------------------------------
__global__ __launch_bounds__(1024) void finalize_kernel(
    const float* __restrict__ partials, float* __restrict__ out) {
  float s = 0.f;
  for (int i = threadIdx.x; i < NPART; i += 1024) s += partials[i];
  #pragma unroll
  for (int off = 32; off; off >>= 1) s += __shfl_down(s, off);
  __shared__ float ws[16];
  if ((threadIdx.x & 63) == 0) ws[threadIdx.x >> 6] = s;
  __syncthreads();
  if (threadIdx.x == 0) {
    float tot = 0.f;
    #pragma unroll
    for (int i = 0; i < 16; ++i) tot += ws[i];
    float mmd = tot / ((float)HALF * (float)HALF);
    out[0] = sqrtf(fmaxf(mmd, 0.f));
  }
}

extern "C" void kernel_launch(void* const* d_in, const int* in_sizes, int n_in,
                              void* d_out, int out_size, void* d_ws, size_t ws_size,
                              hipStream_t stream) {
  const float* Nmat = (const float*)d_in[0];
  const float* Rmat = (const float*)d_in[1];
  float* out = (float*)d_out;

  char* ws = (char*)d_ws;
  unsigned char* Z = (unsigned char*)ws;                     // 16384*256 = 4 MiB
  float* x2       = (float*)(ws + (size_t)MTOT * KDIM);      // 64 KiB
  float* partials = (float*)(ws + (size_t)MTOT * KDIM + MTOT * 4);  // 8 KiB

  convert_kernel<<<MTOT / 4, 256, 0, stream>>>(Nmat, Rmat, (unsigned int*)Z, x2);
  mmd_gemm<<<GRID, 512, 0, stream>>>(Z, x2, partials);
  finalize_kernel<<<1, 1024, 0, stream>>>(partials, out);
}

// Round 10
// 172.117 us; speedup vs baseline: 1.0451x; 1.0451x over previous
//
#include <hip/hip_runtime.h>
#include <hip/hip_bf16.h>
#include <math.h>

typedef float f32x4 __attribute__((ext_vector_type(4)));
typedef int   i32x4 __attribute__((ext_vector_type(4)));
typedef int   i32x8 __attribute__((ext_vector_type(8)));
typedef float f32x2 __attribute__((ext_vector_type(2)));

#define MTOT 16384
#define HALF 8192
#define KDIM 256                  /* bytes per row in fp8 Z */
#define BT 256                    /* tile edge */
#define NB (MTOT / BT)            /* 64 tile-rows */
#define NBLK (NB * (NB + 1) / 2)  /* 2080 upper-triangle tiles */
#define GRID 256                  /* persistent blocks, 1 per CU (130KB LDS) */
#define NPART (GRID * 16)         /* one partial per wave */

#define GLDS16(g, l) __builtin_amdgcn_global_load_lds(                      \
    (const __attribute__((address_space(1))) void*)(g),                     \
    (__attribute__((address_space(3))) void*)(l), 16, 0, 0)

// s_waitcnt immediates (gfx9: vm[3:0] bits3:0, vm[5:4] bits15:14; exp 6:4;
// lgkm 11:8). Unconstrained fields at max.
#define WAIT_VM6()   __builtin_amdgcn_s_waitcnt(0x0F76)  /* vmcnt(6)  */
#define WAIT_VM4()   __builtin_amdgcn_s_waitcnt(0x0F74)  /* vmcnt(4)  */
#define WAIT_VM0()   __builtin_amdgcn_s_waitcnt(0x0F70)  /* vmcnt(0)  */
#define WAIT_LGKM0() __builtin_amdgcn_s_waitcnt(0xC07F)  /* lgkmcnt(0) */
#define BARRIER()    __builtin_amdgcn_s_barrier()

// ---------------------------------------------------------------------------
// Pass 1: fp32 -> fp8 e4m3 (OCP, HW cvt); row norms FROM the quantized
// values so the kernel-matrix diagonal cancels to d2 ~ 0 despite fp8 MFMA.
// ---------------------------------------------------------------------------
__global__ __launch_bounds__(256) void convert_kernel(
    const float* __restrict__ Nmat, const float* __restrict__ Rmat,
    unsigned int* __restrict__ Z, float* __restrict__ x2) {
  const int lane = threadIdx.x & 63;
  const int wv = threadIdx.x >> 6;
  const int row = blockIdx.x * 4 + wv;          // 0..16383
  const float* src = (row < HALF) ? (Nmat + (size_t)row * KDIM)
                                  : (Rmat + (size_t)(row - HALF) * KDIM);
  float4 v = *(const float4*)(src + lane * 4);
  int pk = __builtin_amdgcn_cvt_pk_fp8_f32(v.x, v.y, 0, false);
  pk = __builtin_amdgcn_cvt_pk_fp8_f32(v.z, v.w, pk, true);
  Z[(size_t)row * (KDIM / 4) + lane] = (unsigned int)pk;
  f32x2 d01 = __builtin_amdgcn_cvt_pk_f32_fp8(pk, false);
  f32x2 d23 = __builtin_amdgcn_cvt_pk_f32_fp8(pk, true);
  float sq = d01[0] * d01[0] + d01[1] * d01[1] + d23[0] * d23[0] + d23[1] * d23[1];
  #pragma unroll
  for (int off = 32; off; off >>= 1) sq += __shfl_down(sq, off);
  if (lane == 0) x2[row] = sq;
}

// One K=128 MFMA step over a staged half (straight-line, constant indices).
// R5-verified fragment geometry: lane (fr,fq) reads row-bytes [fq*32,+32) =
// chunks 2fq, 2fq+1 at XOR-swizzled slots.
#define COMPUTE_HALF(as, bs)                                                  \
  {                                                                           \
    i32x8 bf[4];                                                              \
    _Pragma("unroll")                                                         \
    for (int tn = 0; tn < 4; ++tn) {                                          \
      int row = wn * 64 + tn * 16 + fr;                                       \
      const unsigned char* rb = (bs) + row * 128;                             \
      i32x4 lo = *(const i32x4*)(rb + (((2 * fq) ^ key) * 16));               \
      i32x4 hi = *(const i32x4*)(rb + (((2 * fq + 1) ^ key) * 16));           \
      bf[tn] = __builtin_shufflevector(lo, hi, 0, 1, 2, 3, 4, 5, 6, 7);       \
    }                                                                         \
    _Pragma("unroll")                                                         \
    for (int tm = 0; tm < 4; ++tm) {                                          \
      int row = wm * 64 + tm * 16 + fr;                                       \
      const unsigned char* rb = (as) + row * 128;                             \
      i32x4 lo = *(const i32x4*)(rb + (((2 * fq) ^ key) * 16));               \
      i32x4 hi = *(const i32x4*)(rb + (((2 * fq + 1) ^ key) * 16));           \
      i32x8 af = __builtin_shufflevector(lo, hi, 0, 1, 2, 3, 4, 5, 6, 7);     \
      _Pragma("unroll")                                                       \
      for (int tn = 0; tn < 4; ++tn)                                          \
        acc[tm][tn] = __builtin_amdgcn_mfma_scale_f32_16x16x128_f8f6f4(       \
            af, bf[tn], acc[tm][tn], 0, 0,                                    \
            0, 0x7F7F7F7F, 0, 0x7F7F7F7F);                                    \
    }                                                                         \
  }

// ---------------------------------------------------------------------------
// Pass 2: persistent 256x256-tile Z Z^T (MX-fp8 16x16x128, unit scales),
// 2-deep K-half pipeline, raw s_barrier + manual vmcnt (logic proven R6-R9).
//
// REGISTER FIX (R6-R9 lesson): the backend pins this kernel at a 128-reg/
// wave budget no matter what attributes we pass; an acc[8][4] live set
// (~230) therefore ALWAYS spills (~80 MB scratch = the whole regression).
// Instead of fighting the allocator, shrink the live set: 16 waves (1024
// threads) in a 4x4 grid, 64x64 per wave -> acc[4][4]=64 regs + bf 32 +
// af 8 + misc ~= 120 < 128 (the R5 profile, measured VGPR=88 analog).
//
// Per-wave GLDS groups: h0=4, h1=4, x2=2 => loop-top wait vmcnt(6)
// (younger = h1+x2), mid wait vmcnt(4) (younger = next h0), last vmcnt(0).
// ---------------------------------------------------------------------------
__global__ __launch_bounds__(1024) void mmd_gemm(
    const unsigned char* __restrict__ Z, const float* __restrict__ x2,
    float* __restrict__ partials) {
  __shared__ unsigned char As0[BT * 128], Bs0[BT * 128];  // K-half 0, 64 KB
  __shared__ unsigned char As1[BT * 128], Bs1[BT * 128];  // K-half 1, 64 KB
  __shared__ float Xr[BT], Xc[BT];                        // x2 of tile rows/cols

  const int tid  = threadIdx.x;
  const int lane = tid & 63;
  const int wid  = tid >> 6;       // 0..15
  const int wm   = wid >> 2;       // wave row (0..3): rows wm*64..+64
  const int wn   = wid & 3;        // wave col (0..3): cols wn*64..+64
  const int fr   = lane & 15;
  const int fq   = lane >> 4;      // 0..3
  const int lr   = lane >> 3;      // staging local row 0..7
  const int ls   = lane & 7;       // staging slot 0..7
  const int key  = fr & 7;         // read-side bank-swizzle key

  // Stage one K-half: 4 GLDS16 per wave (2 A + 2 B). Instr i (0..31) covers
  // rows 8i..8i+7; slot ls of row gr holds chunk ls^(gr&7) (gr&7 == lr).
  auto issue_half = [&](const unsigned char* Ab, const unsigned char* Bb,
                        int kk, unsigned char* as, unsigned char* bs) {
    #pragma unroll
    for (int q = 0; q < 2; ++q) {
      int i = wid * 2 + q;
      int gr = i * 8 + lr;
      int c = ls ^ lr;
      GLDS16(Ab + (size_t)gr * KDIM + kk + c * 16, as + i * 1024);
    }
    #pragma unroll
    for (int q = 0; q < 2; ++q) {
      int i = wid * 2 + q;
      int gr = i * 8 + lr;
      int c = ls ^ lr;
      GLDS16(Bb + (size_t)gr * KDIM + kk + c * 16, bs + i * 1024);
    }
  };

  // Stage x2 row/col slices: 2 GLDS16 per wave (all 16 waves write identical
  // data to the same LDS - benign; keeps per-wave vmcnt counts uniform).
  auto issue_x2 = [&](int bm_, int bn_) {
    GLDS16(x2 + bm_ * BT + lane * 4, Xr);
    GLDS16(x2 + bn_ * BT + lane * 4, Xc);
  };

  auto decode = [](int t, int& bm_, int& bn_) {
    int u = NBLK - 1 - t;
    int rr = (int)((sqrtf(8.0f * (float)u + 1.0f) - 1.0f) * 0.5f);
    while (rr * (rr + 1) / 2 > u) --rr;
    while ((rr + 1) * (rr + 2) / 2 <= u) ++rr;
    bm_ = NB - 1 - rr;
    bn_ = bm_ + (t - (bm_ * NB - bm_ * (bm_ - 1) / 2));
  };

  float total = 0.f;

  int idx = blockIdx.x;
  int bm, bn;
  decode(idx, bm, bn);
  const unsigned char* Ab = Z + (size_t)bm * BT * KDIM;
  const unsigned char* Bb = Z + (size_t)bn * BT * KDIM;
  issue_half(Ab, Bb, 0,   As0, Bs0);   // 4/wave
  issue_half(Ab, Bb, 128, As1, Bs1);   // 4/wave
  issue_x2(bm, bn);                    // 2/wave

  while (true) {
    const int nidx = idx + GRID;
    const bool haveNext = (nidx < NBLK);
    int nm = 0, nn = 0;
    const unsigned char *nAb = nullptr, *nBb = nullptr;
    if (haveNext) {
      decode(nidx, nm, nn);
      nAb = Z + (size_t)nm * BT * KDIM;
      nBb = Z + (size_t)nn * BT * KDIM;
    }

    f32x4 acc[4][4];
    #pragma unroll
    for (int i = 0; i < 4; ++i)
      #pragma unroll
      for (int j = 0; j < 4; ++j)
        acc[i][j] = (f32x4){0.f, 0.f, 0.f, 0.f};

    WAIT_VM6();                 // h0 done (younger: h1=4 + x2=2)
    BARRIER();
    COMPUTE_HALF(As0, Bs0);
    WAIT_LGKM0();               // my buf0 reads retired
    BARRIER();                  // everyone's buf0 reads retired
    if (haveNext) issue_half(nAb, nBb, 0, As0, Bs0);   // prefetch next h0

    WAIT_VM4();                 // h1 + x2 done (younger: next h0 = 4)...
    if (!haveNext) WAIT_VM0();  // ...or full drain on the last tile
    BARRIER();
    COMPUTE_HALF(As1, Bs1);

    // Epilogue (LDS-only): m = 2s - x2r - x2c = -d2; exp iff any m > -80.
    float amax = -1e30f;
    #pragma unroll
    for (int tm = 0; tm < 4; ++tm) {
      float4 xr = *(const float4*)(Xr + wm * 64 + tm * 16 + fq * 4);
      #pragma unroll
      for (int tn = 0; tn < 4; ++tn) {
        float xc = Xc[wn * 64 + tn * 16 + fr];
        #pragma unroll
        for (int v = 0; v < 4; ++v) {
          float m = 2.f * acc[tm][tn][v] - ((const float*)&xr)[v] - xc;
          amax = fmaxf(amax, m);
        }
      }
    }
    if (__any(amax > -80.f)) {
      float wgt = ((bm < NB / 2) == (bn < NB / 2)) ? 1.f : -1.f;
      if (bm != bn) wgt *= 2.f;
      float p = 0.f;
      #pragma unroll
      for (int tm = 0; tm < 4; ++tm) {
        float4 xr = *(const float4*)(Xr + wm * 64 + tm * 16 + fq * 4);
        #pragma unroll
        for (int tn = 0; tn < 4; ++tn) {
          float xc = Xc[wn * 64 + tn * 16 + fr];
          #pragma unroll
          for (int v = 0; v < 4; ++v) {
            float m = 2.f * acc[tm][tn][v] - ((const float*)&xr)[v] - xc;
            p += exp2f(fminf(m, 0.f) * 1.442695041f);
          }
        }
      }
      total += p * wgt;
    }

    WAIT_LGKM0();               // my buf1/Xr/Xc reads retired
    BARRIER();                  // everyone's retired
    if (!haveNext) break;
    issue_half(nAb, nBb, 128, As1, Bs1);   // prefetch next h1 (4/wave)
    issue_x2(nm, nn);                      // prefetch next x2 (2/wave)
    idx = nidx; bm = nm; bn = nn; Ab = nAb; Bb = nBb;
  }

  #pragma unroll
  for (int off = 32; off; off >>= 1) total += __shfl_down(total, off);
  if (lane == 0) partials[blockIdx.x * 16 + wid] = total;
}

// ---------------------------------------------------------------------------
// Pass 3: reduce the 4096 per-wave partials, sqrt, store the scalar.
// ---------------------------------------------------------------------------
__global__ __launch_bounds__(1024) void finalize_kernel(
    const float* __restrict__ partials, float* __restrict__ out) {
  float s = 0.f;
  for (int i = threadIdx.x; i < NPART; i += 1024) s += partials[i];
  #pragma unroll
  for (int off = 32; off; off >>= 1) s += __shfl_down(s, off);
  __shared__ float ws[16];
  if ((threadIdx.x & 63) == 0) ws[threadIdx.x >> 6] = s;
  __syncthreads();
  if (threadIdx.x == 0) {
    float tot = 0.f;
    #pragma unroll
    for (int i = 0; i < 16; ++i) tot += ws[i];
    float mmd = tot / ((float)HALF * (float)HALF);
    out[0] = sqrtf(fmaxf(mmd, 0.f));
  }
}

extern "C" void kernel_launch(void* const* d_in, const int* in_sizes, int n_in,
                              void* d_out, int out_size, void* d_ws, size_t ws_size,
                              hipStream_t stream) {
  const float* Nmat = (const float*)d_in[0];
  const float* Rmat = (const float*)d_in[1];
  float* out = (float*)d_out;

  char* ws = (char*)d_ws;
  unsigned char* Z = (unsigned char*)ws;                     // 16384*256 = 4 MiB
  float* x2       = (float*)(ws + (size_t)MTOT * KDIM);      // 64 KiB
  float* partials = (float*)(ws + (size_t)MTOT * KDIM + MTOT * 4);  // 16 KiB

  convert_kernel<<<MTOT / 4, 256, 0, stream>>>(Nmat, Rmat, (unsigned int*)Z, x2);
  mmd_gemm<<<GRID, 1024, 0, stream>>>(Z, x2, partials);
  finalize_kernel<<<1, 1024, 0, stream>>>(partials, out);
}